// Round 9
// baseline (5083.769 us; speedup 1.0000x reference)
//
#include <hip/hip_runtime.h>
#include <hip/hip_bf16.h>
#include <math.h>

// Problem constants
#define B_    32
#define FIN   16
#define LIN   8192
#define LAT   64
#define L1V   8190      // length after k=3 valid conv
#define PN    200
#define PLEN  16
#define LOV   8175      // L1V - 16 + 1
#define NCLS  10
#define EPSV  1e-4f
#define MD0   320       // f32 offset of min_distances in d_out
#define PG    25        // protos per block
#define CHP   224       // positions per chunk
#define WIN   240       // window slots per chunk (CHP + 15, padded)
#define NCHK  37        // ceil(8175 / 224)
#define NSL   4         // position slices (blockIdx.z)

typedef unsigned int u32;

// K0: wsm[i] = FLT_MAX bits (unsigned-order identity for atomicMin; overwrites 0xAA poison)
__global__ void k_init(u32* __restrict__ wsm) {
    int i = blockIdx.x * 256 + threadIdx.x;
    if (i < B_ * PN) wsm[i] = 0x7f7fffffu;
}

// K1: block = (proto-group pg, batch b, slice sl). All-f32 pipeline.
// Streams chunks ci = sl, sl+4, ...: fused encoder+addon into LDS (f32 exact),
// sliding patch-norm, 25-proto distance dots, block-min, one atomicMin per cell.
__global__ void __launch_bounds__(256) k_dist(const float* __restrict__ x,
                                              const float* __restrict__ we,
                                              const float* __restrict__ wa,
                                              const float* __restrict__ pt,
                                              u32* __restrict__ wsm) {
    __shared__ float fwin[LAT * WIN];   // 61440 B
    __shared__ float gwin[WIN];         // 960 B
    __shared__ float p2s[32];           // 128 B
    __shared__ float wred[4 * PG];      // 400 B  (total 62928 B)

    const int t     = threadIdx.x;
    const int pg    = blockIdx.x;       // 0..7
    const int b     = blockIdx.y;       // 0..31
    const int sl    = blockIdx.z;       // 0..3
    const int pbase = pg * PG;
    const float* xb = x + (size_t)b * FIN * LIN;

    // ||proto||^2 for this block's 25 protos
    if (t < PG) {
        const float* pr = pt + (size_t)(pbase + t) * (LAT * PLEN);
        float s = 0.f;
        #pragma unroll 1
        for (int i = 0; i < LAT * PLEN; ++i) s += pr[i] * pr[i];
        p2s[t] = s;
    }

    float mn[PG];
    #pragma unroll
    for (int p = 0; p < PG; ++p) mn[p] = 3.4e38f;   // min-identity; >=9 real updates/thread guaranteed

    for (int ci = sl; ci < NCHK; ci += NSL) {
        const int base = ci * CHP;
        __syncthreads();                 // protects fwin/gwin reuse (and p2s on first iter)

        // fused encoder + addon for WIN positions (f32 exact)
        if (t < WIN) {
            const int pos = base + t;
            float acc[LAT];
            #pragma unroll
            for (int o = 0; o < LAT; ++o) acc[o] = 0.f;
            if (pos < L1V) {
                float xw[FIN * 3];
                #pragma unroll
                for (int c2 = 0; c2 < FIN; ++c2) {
                    xw[c2 * 3 + 0] = xb[(size_t)c2 * LIN + pos + 0];
                    xw[c2 * 3 + 1] = xb[(size_t)c2 * LIN + pos + 1];
                    xw[c2 * 3 + 2] = xb[(size_t)c2 * LIN + pos + 2];
                }
                #pragma unroll 1
                for (int c = 0; c < LAT; ++c) {
                    const float* w = we + c * 48;    // uniform -> s_loads
                    float f1 = 0.f;
                    #pragma unroll
                    for (int q = 0; q < 48; ++q) f1 += xw[q] * w[q];
                    f1 = fmaxf(f1, 0.f);
                    #pragma unroll
                    for (int o = 0; o < LAT; ++o)
                        acc[o] += f1 * wa[o * LAT + c];   // uniform -> s_loads
                }
            }
            float gs = 0.f;
            #pragma unroll
            for (int o = 0; o < LAT; ++o) {
                float r = fmaxf(acc[o], 0.f);
                fwin[o * WIN + t] = r;
                gs += r * r;
            }
            gwin[t] = gs;
        }
        __syncthreads();

        // distances for CHP positions x 25 protos
        if (t < CHP) {
            float sv = 0.f;
            #pragma unroll
            for (int k = 0; k < PLEN; ++k) sv += gwin[t + k];

            float acc2[PG];
            #pragma unroll
            for (int p = 0; p < PG; ++p) acc2[p] = 0.f;

            #pragma unroll 1
            for (int c = 0; c < LAT; ++c) {
                float fv[PLEN];
                #pragma unroll
                for (int k = 0; k < PLEN; ++k) fv[k] = fwin[c * WIN + t + k];
                #pragma unroll
                for (int p = 0; p < PG; ++p) {
                    const float* pv = pt + (size_t)(pbase + p) * (LAT * PLEN) + c * PLEN; // uniform
                    float a = acc2[p];
                    #pragma unroll
                    for (int k = 0; k < PLEN; ++k) a += fv[k] * pv[k];
                    acc2[p] = a;
                }
            }
            if (base + t < LOV) {
                #pragma unroll
                for (int p = 0; p < PG; ++p)
                    mn[p] = fminf(mn[p], sv - 2.f * acc2[p] + p2s[p]);
            }
        }
    }

    // block min: wave shfl + tiny LDS merge, then one device-scope atomic per cell
    const int lane = t & 63, wv = t >> 6;
    #pragma unroll
    for (int p = 0; p < PG; ++p) {
        float v = mn[p];
        #pragma unroll
        for (int off = 1; off < 64; off <<= 1) v = fminf(v, __shfl_xor(v, off));
        if (lane == 0) wred[wv * PG + p] = v;
    }
    __syncthreads();
    if (t < PG) {
        float v = fminf(fminf(wred[t], wred[PG + t]),
                        fminf(wred[2 * PG + t], wred[3 * PG + t]));
        v = fmaxf(v, 0.f);                       // relu(min) = min(relu); scrubs negatives/NaN
        atomicMin(&wsm[b * PN + pbase + t], (u32)__float_as_uint(v));  // >=0: uint order = float order
    }
}

// K2: SINGLE block = sole writer of d_out (FLOAT32 layout: [0:320) logits, [320:6720) md).
__global__ void __launch_bounds__(256) k_head(const u32* __restrict__ wsm,
                                              const float* __restrict__ lw,
                                              float* __restrict__ out) {
    __shared__ float as_[B_ * PN];   // 25600 B
    const int t = threadIdx.x;
    for (int i = t; i < B_ * PN; i += 256) {
        float md = __uint_as_float(wsm[i]);
        md = fminf(fmaxf(md, 0.f), 2000.f);      // true md ~450 max; hard bound
        if (!(md == md)) md = 0.f;
        out[MD0 + i] = md;                       // f32 store
        as_[i] = logf((md + 1.f) / (md + EPSV));
    }
    __syncthreads();
    for (int j = t; j < B_ * NCLS; j += 256) {
        const int b = j / NCLS, cl = j - b * NCLS;
        float sum = 0.f;
        #pragma unroll 1
        for (int p = 0; p < PN; ++p) sum += as_[b * PN + p] * lw[cl * PN + p];
        sum = fminf(fmaxf(sum, -100.f), 100.f);  // true |logits| <= ~5
        if (!(sum == sum)) sum = 0.f;
        out[j] = sum;                            // f32 store
    }
}

extern "C" void kernel_launch(void* const* d_in, const int* in_sizes, int n_in,
                              void* d_out, int out_size, void* d_ws, size_t ws_size,
                              hipStream_t stream) {
    // Inputs are FLOAT32. Resolve by unique element count (order-proof).
    const float* x  = 0;   // 32*16*8192 = 4194304
    const float* we = 0;   // 64*16*3    = 3072
    const float* wa = 0;   // 64*64*1    = 4096
    const float* pt = 0;   // 200*64*16  = 204800
    const float* lw = 0;   // 10*200     = 2000
    for (int i = 0; i < n_in; ++i) {
        switch (in_sizes[i]) {
            case 4194304: x  = (const float*)d_in[i]; break;
            case 3072:    we = (const float*)d_in[i]; break;
            case 4096:    wa = (const float*)d_in[i]; break;
            case 204800:  pt = (const float*)d_in[i]; break;
            case 2000:    lw = (const float*)d_in[i]; break;
            default: break;
        }
    }
    if (!x || !we || !wa || !pt || !lw) {   // fallback: documented dict order
        x  = (const float*)d_in[0];
        we = (const float*)d_in[1];
        wa = (const float*)d_in[2];
        pt = (const float*)d_in[3];
        lw = (const float*)d_in[4];
    }
    float* out = (float*)d_out;   // FLOAT32: [0:320) logits, [320:6720) min_distances
    u32* wsm = (u32*)d_ws;        // 6400 u32 = 25.6 KB

    k_init<<<dim3(25), dim3(256), 0, stream>>>(wsm);
    k_dist<<<dim3(8, 32, 4), dim3(256), 0, stream>>>(x, we, wa, pt, wsm);
    k_head<<<dim3(1), dim3(256), 0, stream>>>(wsm, lw, out);
}

// Round 10
// 4453.216 us; speedup vs baseline: 1.1416x; 1.1416x over previous
//
#include <hip/hip_runtime.h>
#include <hip/hip_bf16.h>
#include <math.h>

// Problem constants
#define B_    32
#define FIN   16
#define LIN   8192
#define LAT   64
#define L1V   8190      // length after k=3 valid conv
#define PN    200
#define PLEN  16
#define LOV   8175      // L1V - 16 + 1
#define NCLS  10
#define EPSV  1e-4f
#define MD0   320       // f32 offset of min_distances in d_out
#define CHK   256       // positions per block
#define WIN   272       // window slots (CHK + 16)
#define PGS   25        // protos per inner group
#define NGRP  8         // groups (8*25 = 200)

typedef unsigned short u16;
typedef unsigned int   u32;

__device__ __forceinline__ float vb2f(u16 h) {
    union { u32 u; float f; } v; v.u = ((u32)h) << 16; return v.f;
}
__device__ __forceinline__ u16 vf2b(float f) {
    union { float f; u32 u; } v; v.f = f;
    u32 u = v.u;
    return (u16)((u + 0x7fffu + ((u >> 16) & 1u)) >> 16);   // RNE
}

// K0: wsm[i] = FLT_MAX bits (atomicMin identity; overwrites 0xAA poison)
__global__ void k_init(u32* __restrict__ wsm) {
    int i = blockIdx.x * 256 + threadIdx.x;
    if (i < B_ * PN) wsm[i] = 0x7f7fffffu;
}

// Fused encoder+addon for one position -> fwin (bf16) + gwin (f32, from UNROUNDED f2).
__device__ __forceinline__ void enc_pos(int pos, int slot,
                                        const float* __restrict__ xb,
                                        const float* __restrict__ we,
                                        const float* __restrict__ wa,
                                        u16* __restrict__ fwin,
                                        float* __restrict__ gwin) {
    float acc[LAT];
    #pragma unroll
    for (int o = 0; o < LAT; ++o) acc[o] = 0.f;
    if (pos < L1V) {
        float xw[FIN * 3];
        #pragma unroll
        for (int c2 = 0; c2 < FIN; ++c2) {
            xw[c2 * 3 + 0] = xb[(size_t)c2 * LIN + pos + 0];
            xw[c2 * 3 + 1] = xb[(size_t)c2 * LIN + pos + 1];
            xw[c2 * 3 + 2] = xb[(size_t)c2 * LIN + pos + 2];
        }
        #pragma unroll 1
        for (int c = 0; c < LAT; ++c) {
            const float* w = we + c * 48;        // uniform -> s_loads
            float f1 = 0.f;
            #pragma unroll
            for (int q = 0; q < 48; ++q) f1 += xw[q] * w[q];
            f1 = fmaxf(f1, 0.f);
            #pragma unroll
            for (int o = 0; o < LAT; ++o)
                acc[o] += f1 * wa[o * LAT + c];  // uniform -> s_loads
        }
    }
    float gs = 0.f;
    #pragma unroll
    for (int o = 0; o < LAT; ++o) {
        float r = fmaxf(acc[o], 0.f);            // f32 f2 value
        fwin[o * WIN + slot] = vf2b(r);          // bf16 copy for xp dot only
        gs += r * r;                             // s stays f32-exact
    }
    gwin[slot] = gs;
}

// K1: block = (chunk ck of 256 positions, batch b). Encoder ONCE into LDS,
// then 8 proto-groups x 25 protos against the same window. 1024 blocks = 4/CU.
__global__ void __launch_bounds__(256) k_dist(const float* __restrict__ x,
                                              const float* __restrict__ we,
                                              const float* __restrict__ wa,
                                              const float* __restrict__ pt,
                                              u32* __restrict__ wsm) {
    __shared__ u16   fwin[LAT * WIN];   // 34816 B (bf16)
    __shared__ float gwin[WIN];         // 1088 B
    __shared__ float p2all[PN];         // 800 B
    __shared__ float wred[4 * PGS];     // 400 B   (~37.1 KB -> 4 blocks/CU)

    const int t  = threadIdx.x;
    const int ck = blockIdx.x;          // 0..31
    const int b  = blockIdx.y;          // 0..31
    const int base = ck * CHK;
    const float* xb = x + (size_t)b * FIN * LIN;

    // ||proto||^2 for all 200 protos (once per block)
    if (t < PN) {
        const float* pr = pt + (size_t)t * (LAT * PLEN);
        float s = 0.f;
        #pragma unroll 1
        for (int i = 0; i < LAT * PLEN; ++i) s += pr[i] * pr[i];
        p2all[t] = s;
    }

    // f2 window: 272 slots (each thread 1, first 16 threads take the tail)
    enc_pos(base + t, t, xb, we, wa, fwin, gwin);
    if (t < 16) enc_pos(base + CHK + t, CHK + t, xb, we, wa, fwin, gwin);
    __syncthreads();

    // sliding patch-norm for this thread's position (f32 exact)
    float sv = 0.f;
    #pragma unroll
    for (int k = 0; k < PLEN; ++k) sv += gwin[t + k];
    const bool valid = (base + t) < LOV;

    const int lane = t & 63, wv = t >> 6;

    #pragma unroll 1
    for (int g = 0; g < NGRP; ++g) {
        const int pbase = g * PGS;

        float acc[PGS];
        #pragma unroll
        for (int p = 0; p < PGS; ++p) acc[p] = 0.f;

        #pragma unroll 1
        for (int c = 0; c < LAT; ++c) {
            float fv[PLEN];
            #pragma unroll
            for (int k = 0; k < PLEN; ++k) fv[k] = vb2f(fwin[c * WIN + t + k]);
            const float* pv = pt + (size_t)pbase * (LAT * PLEN) + c * PLEN;  // uniform
            #pragma unroll
            for (int p = 0; p < PGS; ++p) {
                float a = acc[p];
                #pragma unroll
                for (int k = 0; k < PLEN; ++k) a += fv[k] * pv[p * (LAT * PLEN) + k];
                acc[p] = a;
            }
        }

        // per-proto block min -> one atomic per (cell, block)
        #pragma unroll
        for (int p = 0; p < PGS; ++p) {
            float d = valid ? (sv - 2.f * acc[p] + p2all[pbase + p]) : 3.4e38f;
            #pragma unroll
            for (int off = 1; off < 64; off <<= 1) d = fminf(d, __shfl_xor(d, off));
            if (lane == 0) wred[wv * PGS + p] = d;
        }
        __syncthreads();
        if (t < PGS) {
            float v = fminf(fminf(wred[t], wred[PGS + t]),
                            fminf(wred[2 * PGS + t], wred[3 * PGS + t]));
            v = fmaxf(v, 0.f);   // relu(min) = min(relu); scrubs negatives/NaN
            atomicMin(&wsm[b * PN + pbase + t], (u32)__float_as_uint(v));
        }
        __syncthreads();         // wred safe for next group
    }
}

// K2: one block per batch; sole writer of d_out (f32: [0:320) logits, [320:6720) md).
__global__ void __launch_bounds__(256) k_head(const u32* __restrict__ wsm,
                                              const float* __restrict__ lw,
                                              float* __restrict__ out) {
    __shared__ float as_[PN];
    const int b = blockIdx.x, t = threadIdx.x;
    if (t < PN) {
        float md = __uint_as_float(wsm[b * PN + t]);
        md = fminf(fmaxf(md, 0.f), 2000.f);
        if (!(md == md)) md = 0.f;
        out[MD0 + b * PN + t] = md;
        as_[t] = logf((md + 1.f) / (md + EPSV));
    }
    __syncthreads();
    if (t < NCLS) {
        float sum = 0.f;
        #pragma unroll 1
        for (int p = 0; p < PN; ++p) sum += as_[p] * lw[t * PN + p];
        sum = fminf(fmaxf(sum, -100.f), 100.f);
        if (!(sum == sum)) sum = 0.f;
        out[b * NCLS + t] = sum;
    }
}

extern "C" void kernel_launch(void* const* d_in, const int* in_sizes, int n_in,
                              void* d_out, int out_size, void* d_ws, size_t ws_size,
                              hipStream_t stream) {
    // Inputs are FLOAT32. Resolve by unique element count (order-proof).
    const float* x  = 0;   // 32*16*8192 = 4194304
    const float* we = 0;   // 64*16*3    = 3072
    const float* wa = 0;   // 64*64*1    = 4096
    const float* pt = 0;   // 200*64*16  = 204800
    const float* lw = 0;   // 10*200     = 2000
    for (int i = 0; i < n_in; ++i) {
        switch (in_sizes[i]) {
            case 4194304: x  = (const float*)d_in[i]; break;
            case 3072:    we = (const float*)d_in[i]; break;
            case 4096:    wa = (const float*)d_in[i]; break;
            case 204800:  pt = (const float*)d_in[i]; break;
            case 2000:    lw = (const float*)d_in[i]; break;
            default: break;
        }
    }
    if (!x || !we || !wa || !pt || !lw) {
        x  = (const float*)d_in[0];
        we = (const float*)d_in[1];
        wa = (const float*)d_in[2];
        pt = (const float*)d_in[3];
        lw = (const float*)d_in[4];
    }
    float* out = (float*)d_out;   // f32: [0:320) logits, [320:6720) min_distances
    u32* wsm = (u32*)d_ws;        // 6400 u32

    k_init<<<dim3(25), dim3(256), 0, stream>>>(wsm);
    k_dist<<<dim3(32, 32), dim3(256), 0, stream>>>(x, we, wa, pt, wsm);
    k_head<<<dim3(B_), dim3(256), 0, stream>>>(wsm, lw, out);
}

// Round 11
// 694.966 us; speedup vs baseline: 7.3151x; 6.4078x over previous
//
#include <hip/hip_runtime.h>
#include <hip/hip_bf16.h>
#include <math.h>

// Problem constants
#define B_    32
#define FIN   16
#define LIN   8192
#define LAT   64
#define L1V   8190      // length after k=3 valid conv
#define PN    200
#define PLEN  16
#define LOV   8175      // L1V - 16 + 1
#define NCLS  10
#define EPSV  1e-4f
#define MD0   320       // f32 offset of min_distances in d_out
#define CHK   256       // positions per block
#define WIN   272       // window slots (CHK + 16)
#define FST   68        // fwin row stride in u16 (136 B: 2-way bank aliasing = free)
#define PST   68        // proto-stage row stride in u16
#define NPT   7         // proto tiles of 32 (200 padded to 224)

typedef unsigned short u16;
typedef unsigned int   u32;
typedef short s16x8 __attribute__((ext_vector_type(8)));   // 8 bf16 (4 VGPRs)
typedef float f32x16 __attribute__((ext_vector_type(16))); // 32x32 MFMA accumulator

union FragU { uint2 u2[2]; s16x8 v; };

__device__ __forceinline__ u16 vf2b(float f) {
    union { float f; u32 u; } v; v.f = f;
    u32 u = v.u;
    return (u16)((u + 0x7fffu + ((u >> 16) & 1u)) >> 16);   // RNE
}

// K0: wsm[0:6400] = FLT_MAX bits (atomicMin identity); p2g[0:224] = ||proto||^2 (f32, batch-indep)
__global__ void k_init(const float* __restrict__ pt, u32* __restrict__ wsm,
                       float* __restrict__ p2g) {
    int i = blockIdx.x * 256 + threadIdx.x;
    if (i < B_ * PN) wsm[i] = 0x7f7fffffu;
    else if (i < B_ * PN + 224) {
        int p = i - B_ * PN;
        float s = 0.f;
        if (p < PN) {
            const float4* pr = (const float4*)(pt + (size_t)p * (LAT * PLEN));
            #pragma unroll 4
            for (int j = 0; j < 256; ++j) {
                float4 v = pr[j];
                s += v.x * v.x + v.y * v.y + v.z * v.z + v.w * v.w;
            }
        }
        p2g[p] = s;
    }
}

// Fused encoder+addon for one position -> fwin POSITION-MAJOR bf16 [slot][64ch] + gwin f32.
__device__ __forceinline__ void enc_pos(int pos, int slot,
                                        const float* __restrict__ xb,
                                        const float* __restrict__ we,
                                        const float* __restrict__ wa,
                                        u32* __restrict__ fw32,
                                        float* __restrict__ gwin) {
    float acc[LAT];
    #pragma unroll
    for (int o = 0; o < LAT; ++o) acc[o] = 0.f;
    if (pos < L1V) {
        float xw[FIN * 3];
        #pragma unroll
        for (int c2 = 0; c2 < FIN; ++c2) {
            xw[c2 * 3 + 0] = xb[(size_t)c2 * LIN + pos + 0];
            xw[c2 * 3 + 1] = xb[(size_t)c2 * LIN + pos + 1];
            xw[c2 * 3 + 2] = xb[(size_t)c2 * LIN + pos + 2];
        }
        #pragma unroll 1
        for (int c = 0; c < LAT; ++c) {
            const float* w = we + c * 48;        // uniform -> s_loads
            float f1 = 0.f;
            #pragma unroll
            for (int q = 0; q < 48; ++q) f1 += xw[q] * w[q];
            f1 = fmaxf(f1, 0.f);
            #pragma unroll
            for (int o = 0; o < LAT; ++o)
                acc[o] += f1 * wa[o * LAT + c];  // uniform -> s_loads
        }
    }
    float gs = 0.f;
    #pragma unroll
    for (int o2 = 0; o2 < 32; ++o2) {
        float r0 = fmaxf(acc[2 * o2], 0.f);
        float r1 = fmaxf(acc[2 * o2 + 1], 0.f);
        fw32[slot * (FST / 2) + o2] = ((u32)vf2b(r1) << 16) | (u32)vf2b(r0);
        gs += r0 * r0 + r1 * r1;                 // s stays f32-exact
    }
    gwin[slot] = gs;
}

// K1: block = (chunk of 256 positions, batch). Encoder once into LDS (position-major),
// then tap-decomposed MFMA GEMM: xp = sum_tap P_tap[n][c] * F[c][m+tap].
// Wave = 2 position-tiles of 32; 7 proto-tiles of 32; protos staged 2 taps at a time.
__global__ void __launch_bounds__(256, 3) k_dist(const float* __restrict__ x,
                                                 const float* __restrict__ we,
                                                 const float* __restrict__ wa,
                                                 const float* __restrict__ pt,
                                                 u32* __restrict__ wsm,
                                                 const float* __restrict__ p2g) {
    __shared__ u16   fwin[WIN * FST];    // 36992 B, [slot][ch] bf16
    __shared__ u16   ps[2 * 32 * PST];   // 8704 B,  [tapLocal][p][ch] bf16
    __shared__ float gwin[WIN];          // 1088 B
    __shared__ float sarr[CHK];          // 1024 B   (total 47808 B -> 3 blocks/CU)

    const int t  = threadIdx.x;
    const int ck = blockIdx.x;           // 0..31
    const int b  = blockIdx.y;           // 0..31
    const int base = ck * CHK;
    const float* xb = x + (size_t)b * FIN * LIN;

    // Phase 1: f2 window (272 slots), position-major bf16 + f32 g
    enc_pos(base + t, t, xb, we, wa, (u32*)fwin, gwin);
    if (t < 16) enc_pos(base + CHK + t, CHK + t, xb, we, wa, (u32*)fwin, gwin);
    __syncthreads();

    // Phase 2: sliding patch-norm (invalid positions poisoned with +huge)
    {
        float sv = 0.f;
        #pragma unroll
        for (int k = 0; k < PLEN; ++k) sv += gwin[t + k];
        sarr[t] = (base + t < LOV) ? sv : 3.0e38f;
    }
    __syncthreads();

    const int lane = t & 63;
    const int wv   = t >> 6;             // wave owns positions [wv*64, wv*64+64)
    const int m    = lane & 31;
    const int half = lane >> 5;
    const int koff = half * 8;           // k-chunk within 16-channel MFMA step

    #pragma unroll 1
    for (int p7 = 0; p7 < NPT; ++p7) {
        f32x16 acc0, acc1;
        #pragma unroll
        for (int i = 0; i < 16; ++i) { acc0[i] = 0.f; acc1[i] = 0.f; }

        #pragma unroll 1
        for (int tg = 0; tg < 8; ++tg) {
            // stage taps (tg*2, tg*2+1) for 32 protos: [tl][p][c] bf16
            #pragma unroll
            for (int r = 0; r < 8; ++r) {
                int i = r * 256 + t;
                int p = i >> 6, c = i & 63;
                int gp = p7 * 32 + p;
                float2 v = make_float2(0.f, 0.f);
                if (gp < PN)
                    v = *(const float2*)(pt + (size_t)gp * (LAT * PLEN) + c * PLEN + tg * 2);
                ps[p * PST + c]            = vf2b(v.x);
                ps[32 * PST + p * PST + c] = vf2b(v.y);
            }
            __syncthreads();

            #pragma unroll
            for (int tl = 0; tl < 2; ++tl) {
                const int tap = tg * 2 + tl;
                #pragma unroll
                for (int cs = 0; cs < 4; ++cs) {
                    const int co = cs * 16 + koff;
                    FragU bF, a0, a1;
                    const u16* bp = &ps[tl * (32 * PST) + m * PST + co];
                    bF.u2[0] = *(const uint2*)bp; bF.u2[1] = *(const uint2*)(bp + 4);
                    const u16* ap = &fwin[(wv * 64 + m + tap) * FST + co];
                    a0.u2[0] = *(const uint2*)ap; a0.u2[1] = *(const uint2*)(ap + 4);
                    const u16* aq = ap + 32 * FST;
                    a1.u2[0] = *(const uint2*)aq; a1.u2[1] = *(const uint2*)(aq + 4);
                    acc0 = __builtin_amdgcn_mfma_f32_32x32x16_bf16(a0.v, bF.v, acc0, 0, 0, 0);
                    acc1 = __builtin_amdgcn_mfma_f32_32x32x16_bf16(a1.v, bF.v, acc1, 0, 0, 0);
                }
            }
            __syncthreads();   // all waves done reading ps before restage
        }

        // epilogue: d = s[pos] - 2*xp + p2[proto]; min over this wave's 64 positions
        // C layout (verified m74/m101): col = lane&31, row = (reg&3) + 8*(reg>>2) + 4*(lane>>5)
        const float p2v = p2g[p7 * 32 + m];
        float dmin = 3.4e38f;
        #pragma unroll
        for (int reg = 0; reg < 16; ++reg) {
            const int row = (reg & 3) + 8 * (reg >> 2) + 4 * half;
            float d0 = sarr[wv * 64 + row]      - 2.f * acc0[reg] + p2v;
            float d1 = sarr[wv * 64 + 32 + row] - 2.f * acc1[reg] + p2v;
            dmin = fminf(dmin, fminf(d0, d1));
        }
        dmin = fminf(dmin, __shfl_xor(dmin, 32));   // merge the two half-wave row sets
        if (half == 0 && p7 * 32 + m < PN)
            atomicMin(&wsm[b * PN + p7 * 32 + m], (u32)__float_as_uint(fmaxf(dmin, 0.f)));
    }
}

// K2: one block per batch; sole writer of d_out (f32: [0:320) logits, [320:6720) md).
__global__ void __launch_bounds__(256) k_head(const u32* __restrict__ wsm,
                                              const float* __restrict__ lw,
                                              float* __restrict__ out) {
    __shared__ float as_[PN];
    const int b = blockIdx.x, t = threadIdx.x;
    if (t < PN) {
        float md = __uint_as_float(wsm[b * PN + t]);
        md = fminf(fmaxf(md, 0.f), 2000.f);
        if (!(md == md)) md = 0.f;
        out[MD0 + b * PN + t] = md;
        as_[t] = logf((md + 1.f) / (md + EPSV));
    }
    __syncthreads();
    if (t < NCLS) {
        float sum = 0.f;
        #pragma unroll 1
        for (int p = 0; p < PN; ++p) sum += as_[p] * lw[t * PN + p];
        sum = fminf(fmaxf(sum, -100.f), 100.f);
        if (!(sum == sum)) sum = 0.f;
        out[b * NCLS + t] = sum;
    }
}

extern "C" void kernel_launch(void* const* d_in, const int* in_sizes, int n_in,
                              void* d_out, int out_size, void* d_ws, size_t ws_size,
                              hipStream_t stream) {
    // Inputs are FLOAT32. Resolve by unique element count (order-proof).
    const float* x  = 0;   // 32*16*8192 = 4194304
    const float* we = 0;   // 64*16*3    = 3072
    const float* wa = 0;   // 64*64*1    = 4096
    const float* pt = 0;   // 200*64*16  = 204800
    const float* lw = 0;   // 10*200     = 2000
    for (int i = 0; i < n_in; ++i) {
        switch (in_sizes[i]) {
            case 4194304: x  = (const float*)d_in[i]; break;
            case 3072:    we = (const float*)d_in[i]; break;
            case 4096:    wa = (const float*)d_in[i]; break;
            case 204800:  pt = (const float*)d_in[i]; break;
            case 2000:    lw = (const float*)d_in[i]; break;
            default: break;
        }
    }
    if (!x || !we || !wa || !pt || !lw) {
        x  = (const float*)d_in[0];
        we = (const float*)d_in[1];
        wa = (const float*)d_in[2];
        pt = (const float*)d_in[3];
        lw = (const float*)d_in[4];
    }
    float* out = (float*)d_out;   // f32: [0:320) logits, [320:6720) min_distances
    u32*   wsm = (u32*)d_ws;      // 6400 u32
    float* p2g = (float*)d_ws + B_ * PN;   // 224 f32 (26.5 KB total d_ws use)

    k_init<<<dim3(26), dim3(256), 0, stream>>>(pt, wsm, p2g);
    k_dist<<<dim3(32, 32), dim3(256), 0, stream>>>(x, we, wa, pt, wsm, p2g);
    k_head<<<dim3(B_), dim3(256), 0, stream>>>(wsm, lw, out);
}